// Round 7
// baseline (137.364 us; speedup 1.0000x reference)
//
#include <hip/hip_runtime.h>
#include <hip/hip_bf16.h>

// out[b,s,t] = ||B(x_s - x_t)||^2 = sq[s] + sq[t] - 2*gram[s,t],  p = x @ B^T
// Round 7: projb = BM128xBN256, 2-buffer (48KB -> 3 blocks/CU, grid 768 = one
// residency round), fused sq (shuffle-reduce + atomicAdd, zeroed in cvt_x);
// gram reverted to proven R5 geometry (128^2, 3-buf, vmcnt(4)).

using bf16x8 = __attribute__((ext_vector_type(8))) __bf16;
using f32x4  = __attribute__((ext_vector_type(4))) float;
using fl4    = __attribute__((ext_vector_type(4))) float;
using u16x4  = __attribute__((ext_vector_type(4))) unsigned short;

#define NB 64
#define NS 512
#define NL 768

__device__ __forceinline__ unsigned short f2bf(float f) {
  unsigned u = __builtin_bit_cast(unsigned, f);
  u += 0x7FFFu + ((u >> 16) & 1u); // RNE
  return (unsigned short)(u >> 16);
}

__device__ __forceinline__ void gload_lds16(const void* g, void* l) {
  __builtin_amdgcn_global_load_lds(
      (const __attribute__((address_space(1))) void*)g,
      (__attribute__((address_space(3))) void*)l, 16, 0, 0);
}

#define MEMFENCE asm volatile("" ::: "memory")

// ---------------- kernel 1: convert b (L x L fp32) -> bb bf16 ----------------
__global__ __launch_bounds__(256) void k_cvt_b(const float* __restrict__ b,
                                               unsigned short* __restrict__ bb) {
  const long t = (long)blockIdx.x * 256 + threadIdx.x;
  fl4 v = *(const fl4*)(b + t * 4);
  u16x4 o;
#pragma unroll
  for (int j = 0; j < 4; ++j) o[j] = f2bf(v[j]);
  *(u16x4*)(bb + t * 4) = o;
}

// ------- kernel 1b: convert x -> xb bf16 (lane-contiguous) + zero sq -------
__global__ __launch_bounds__(256) void k_cvt_x(const float* __restrict__ x,
                                               unsigned short* __restrict__ xb,
                                               float* __restrict__ sq) {
  if (blockIdx.x < 128) sq[blockIdx.x * 256 + threadIdx.x] = 0.f;
  const long n4 = (long)NB * NS * NL / 4;
  const long stride = (long)gridDim.x * 256;
  for (long i = (long)blockIdx.x * 256 + threadIdx.x; i < n4; i += stride) {
    fl4 v = *(const fl4*)(x + i * 4);
    u16x4 o;
#pragma unroll
    for (int j = 0; j < 4; ++j) o[j] = f2bf(v[j]);
    *(u16x4*)(xb + i * 4) = o;
  }
}

// ------- kernel 2: p = xb @ bb^T, BM=128 BN=256, 2-buffer, fused sq -------
__global__ __launch_bounds__(256, 3) void k_projb(
    const unsigned short* __restrict__ xb,
    const unsigned short* __restrict__ bb,
    unsigned short* __restrict__ p,
    float* __restrict__ sq) {
  __shared__ __align__(16) unsigned short smA[2][128 * 32]; // 16 KB
  __shared__ __align__(16) unsigned short smB[2][256 * 32]; // 32 KB
  const int tid = threadIdx.x;
  const int w = tid >> 6, l = tid & 63;
  // 768 blocks, 96/XCD; nt fastest: 3 consecutive wgs share the A m-tile
  const int wg = ((blockIdx.x & 7) * 96) + (blockIdx.x >> 3);
  const int nt = wg % 3, mt = wg / 3;
  const long m0 = (long)mt * 128, n0 = (long)nt * 256;
  const int wr = (w >> 1) * 64, wc = (w & 1) * 128;

  const int srow = tid >> 2;
  const int scol = ((tid & 3) ^ ((srow >> 1) & 3)) * 8; // pre-swizzled source
  const unsigned short* gA = xb + (m0 + srow) * (long)NL + scol;
  const unsigned short* gB = bb + (n0 + srow) * (long)NL + scol;

  const int qh = l >> 4, lr = l & 15;
  const int swz = ((qh ^ ((lr >> 1) & 3)) << 4);
  const int aoff = (wr + lr) * 64 + swz;
  const int boff = (wc + lr) * 64 + swz;

  f32x4 acc[4][8] = {};

#define STAGEP(k0, buf)                                                      \
  {                                                                          \
    char* da_ = (char*)&smA[buf][0] + w * 1024;                              \
    char* db_ = (char*)&smB[buf][0] + w * 1024;                              \
    gload_lds16(gA + (k0), da_);                                             \
    gload_lds16(gA + (k0) + 64 * NL, da_ + 4096);                            \
    gload_lds16(gB + (k0), db_);                                             \
    gload_lds16(gB + (k0) + 64 * NL, db_ + 4096);                            \
    gload_lds16(gB + (k0) + 128 * NL, db_ + 8192);                           \
    gload_lds16(gB + (k0) + 192 * NL, db_ + 12288);                          \
  }
#define COMPUTEP(buf)                                                        \
  {                                                                          \
    const char* A_ = (const char*)&smA[buf][0];                              \
    const char* B_ = (const char*)&smB[buf][0];                              \
    bf16x8 fa[4], fb[8];                                                     \
    _Pragma("unroll")                                                        \
    for (int m = 0; m < 4; ++m)                                              \
      fa[m] = *(const bf16x8*)(A_ + aoff + m * 1024);                        \
    _Pragma("unroll")                                                        \
    for (int n = 0; n < 8; ++n)                                              \
      fb[n] = *(const bf16x8*)(B_ + boff + n * 1024);                        \
    _Pragma("unroll")                                                        \
    for (int m = 0; m < 4; ++m)                                              \
      _Pragma("unroll")                                                      \
      for (int n = 0; n < 8; ++n)                                            \
        acc[m][n] = __builtin_amdgcn_mfma_f32_16x16x32_bf16(fa[m], fb[n],    \
                                                            acc[m][n], 0, 0, 0); \
  }

  STAGEP(0, 0)
  asm volatile("s_waitcnt vmcnt(0)" ::: "memory");
  __builtin_amdgcn_s_barrier();
  MEMFENCE;
  int cur = 0;
#pragma unroll 1
  for (int kt = 0; kt < 24; ++kt) {
    if (kt < 23) STAGEP((kt + 1) * 32, cur ^ 1)  // flies over compute
    COMPUTEP(cur)
    if (kt < 23) {
      asm volatile("s_waitcnt vmcnt(0)" ::: "memory"); // next tile staged
      __builtin_amdgcn_s_barrier();
      MEMFENCE;
      cur ^= 1;
    }
  }
#undef STAGEP
#undef COMPUTEP

  // epilogue: C/D layout col = lane&15, row = (lane>>4)*4 + reg.
  // Writes p (bf16) and accumulates sq[row] from the ROUNDED values so the
  // output diagonal stays exactly 0-consistent.
#pragma unroll
  for (int m = 0; m < 4; ++m) {
    const long rbase = m0 + wr + m * 16 + qh * 4;
#pragma unroll
    for (int r = 0; r < 4; ++r) {
      const long row = rbase + r;
      float s = 0.f;
#pragma unroll
      for (int n = 0; n < 8; ++n) {
        const unsigned short us = f2bf(acc[m][n][r]);
        p[row * NL + (n0 + wc + n * 16 + lr)] = us;
        const float f = __builtin_bit_cast(float, ((unsigned)us) << 16);
        s += f * f;
      }
      s += __shfl_xor(s, 1, 64);
      s += __shfl_xor(s, 2, 64);
      s += __shfl_xor(s, 4, 64);
      s += __shfl_xor(s, 8, 64);
      if (lr == 0) atomicAdd(sq + row, s);
    }
  }
}

// ------- kernel 4: per-batch gram (128^2, 3-buf, R5-proven) + epilogue -------
__global__ __launch_bounds__(256) void k_gram(const unsigned short* __restrict__ p,
                                              const float* __restrict__ sq,
                                              float* __restrict__ out) {
  __shared__ __align__(16) unsigned short smA[3][128 * 32];
  __shared__ __align__(16) unsigned short smB[3][128 * 32];
  const int tid = threadIdx.x;
  const int w = tid >> 6, l = tid & 63;
  const int wg = ((blockIdx.x & 7) * 128) + (blockIdx.x >> 3);
  const int batch = wg >> 4, tile = wg & 15;
  const int mt = tile >> 2, nt = tile & 3;
  const unsigned short* pb = p + (long)batch * NS * NL;
  const long m0 = (long)mt * 128, n0 = (long)nt * 128;
  const int wr = (w >> 1) * 64, wc = (w & 1) * 64;

  const int srow = tid >> 2;
  const int scol = ((tid & 3) ^ ((srow >> 1) & 3)) * 8;
  const unsigned short* gA = pb + (m0 + srow) * (long)NL + scol;
  const unsigned short* gB = pb + (n0 + srow) * (long)NL + scol;

  const int qh = l >> 4, lr = l & 15;
  const int aoff = (wr + lr) * 64 + ((qh ^ ((lr >> 1) & 3)) << 4);
  const int boff = (wc + lr) * 64 + ((qh ^ ((lr >> 1) & 3)) << 4);

  f32x4 acc[4][4] = {};

#define STAGE2(k0, buf)                                                      \
  {                                                                          \
    char* da_ = (char*)&smA[buf][0] + w * 1024;                              \
    char* db_ = (char*)&smB[buf][0] + w * 1024;                              \
    gload_lds16(gA + (k0), da_);                                             \
    gload_lds16(gA + (k0) + 64 * NL, da_ + 4096);                            \
    gload_lds16(gB + (k0), db_);                                             \
    gload_lds16(gB + (k0) + 64 * NL, db_ + 4096);                            \
  }
#define COMPUTE2(buf)                                                        \
  {                                                                          \
    const char* A_ = (const char*)&smA[buf][0];                              \
    const char* B_ = (const char*)&smB[buf][0];                              \
    bf16x8 fa[4], fb[4];                                                     \
    _Pragma("unroll")                                                        \
    for (int m = 0; m < 4; ++m)                                              \
      fa[m] = *(const bf16x8*)(A_ + aoff + m * 1024);                        \
    _Pragma("unroll")                                                        \
    for (int n = 0; n < 4; ++n)                                              \
      fb[n] = *(const bf16x8*)(B_ + boff + n * 1024);                        \
    _Pragma("unroll")                                                        \
    for (int m = 0; m < 4; ++m)                                              \
      _Pragma("unroll")                                                      \
      for (int n = 0; n < 4; ++n)                                            \
        acc[m][n] = __builtin_amdgcn_mfma_f32_16x16x32_bf16(fa[m], fb[n],    \
                                                            acc[m][n], 0, 0, 0); \
  }

  STAGE2(0, 0)
  STAGE2(32, 1)
  int cur = 0, nxt2 = 2;
#pragma unroll 1
  for (int kt = 0; kt < 23; ++kt) {
    asm volatile("s_waitcnt vmcnt(4)" ::: "memory");
    __builtin_amdgcn_s_barrier();
    MEMFENCE;
    if (kt < 22) STAGE2((kt + 2) * 32, nxt2)
    COMPUTE2(cur)
    cur = (cur == 2) ? 0 : cur + 1;
    nxt2 = (nxt2 == 2) ? 0 : nxt2 + 1;
  }
  asm volatile("s_waitcnt vmcnt(0)" ::: "memory");
  __builtin_amdgcn_s_barrier();
  MEMFENCE;
  COMPUTE2(cur)
#undef STAGE2
#undef COMPUTE2

  const float* sqb = sq + batch * NS;
  float* outb = out + (long)batch * NS * NS;
  float sqc[4];
#pragma unroll
  for (int n = 0; n < 4; ++n) sqc[n] = sqb[n0 + wc + n * 16 + lr];
#pragma unroll
  for (int m = 0; m < 4; ++m) {
#pragma unroll
    for (int r = 0; r < 4; ++r) {
      const long row = m0 + wr + m * 16 + qh * 4 + r;
      const float sr = sqb[row];
#pragma unroll
      for (int n = 0; n < 4; ++n) {
        const long col = n0 + wc + n * 16 + lr;
        outb[row * NS + col] = sr + sqc[n] - 2.0f * acc[m][n][r];
      }
    }
  }
}

extern "C" void kernel_launch(void* const* d_in, const int* in_sizes, int n_in,
                              void* d_out, int out_size, void* d_ws, size_t ws_size,
                              hipStream_t stream) {
  (void)in_sizes; (void)n_in; (void)out_size; (void)ws_size;
  const float* x = (const float*)d_in[0]; // [B,S,L] fp32
  const float* b = (const float*)d_in[1]; // [L,L] fp32
  float* out = (float*)d_out;             // [B,S,S] fp32
  char* ws = (char*)d_ws;
  unsigned short* bb = (unsigned short*)ws;              //  1,179,648 B
  float* sq          = (float*)(ws + 1179648);           //    131,072 B
  unsigned short* p  = (unsigned short*)(ws + 1310720);  // 50,331,648 B
  unsigned short* xb = (unsigned short*)(ws + 51642368); // 50,331,648 B

  k_cvt_b<<<576, 256, 0, stream>>>(b, bb);
  k_cvt_x<<<2048, 256, 0, stream>>>(x, xb, sq); // also zeroes sq
  k_projb<<<768, 256, 0, stream>>>(xb, bb, p, sq); // 256 m x 3 n, fused sq
  k_gram <<<1024, 256, 0, stream>>>(p, sq, out);   // 64 batches x 16 tiles
}

// Round 8
// 136.023 us; speedup vs baseline: 1.0099x; 1.0099x over previous
//
#include <hip/hip_runtime.h>
#include <hip/hip_bf16.h>

// out[b,s,t] = ||B(x_s - x_t)||^2 = sq[s] + sq[t] - 2*gram[s,t],  p = x @ B^T
// Round 8: assembly of proven-best parts. projb = R5-exact (128^2, 3-buf,
// counted vmcnt(4)) + fused-sq epilogue (single new variable). gram = R5-exact.
// cvt_x = R6 lane-contiguous (+ sq zeroing). k_sq eliminated.

using bf16x8 = __attribute__((ext_vector_type(8))) __bf16;
using f32x4  = __attribute__((ext_vector_type(4))) float;
using fl4    = __attribute__((ext_vector_type(4))) float;
using u16x4  = __attribute__((ext_vector_type(4))) unsigned short;

#define NB 64
#define NS 512
#define NL 768

__device__ __forceinline__ unsigned short f2bf(float f) {
  unsigned u = __builtin_bit_cast(unsigned, f);
  u += 0x7FFFu + ((u >> 16) & 1u); // RNE
  return (unsigned short)(u >> 16);
}

__device__ __forceinline__ void gload_lds16(const void* g, void* l) {
  __builtin_amdgcn_global_load_lds(
      (const __attribute__((address_space(1))) void*)g,
      (__attribute__((address_space(3))) void*)l, 16, 0, 0);
}

#define MEMFENCE asm volatile("" ::: "memory")

// ---------------- kernel 1: convert b (L x L fp32) -> bb bf16 ----------------
__global__ __launch_bounds__(256) void k_cvt_b(const float* __restrict__ b,
                                               unsigned short* __restrict__ bb) {
  const long t = (long)blockIdx.x * 256 + threadIdx.x;
  fl4 v = *(const fl4*)(b + t * 4);
  u16x4 o;
#pragma unroll
  for (int j = 0; j < 4; ++j) o[j] = f2bf(v[j]);
  *(u16x4*)(bb + t * 4) = o;
}

// ------- kernel 1b: convert x -> xb bf16 (lane-contiguous) + zero sq -------
__global__ __launch_bounds__(256) void k_cvt_x(const float* __restrict__ x,
                                               unsigned short* __restrict__ xb,
                                               float* __restrict__ sq) {
  if (blockIdx.x < 128) sq[blockIdx.x * 256 + threadIdx.x] = 0.f;
  const long n4 = (long)NB * NS * NL / 4;
  const long stride = (long)gridDim.x * 256;
  for (long i = (long)blockIdx.x * 256 + threadIdx.x; i < n4; i += stride) {
    fl4 v = *(const fl4*)(x + i * 4); // 16 B/lane, lanes contiguous
    u16x4 o;
#pragma unroll
    for (int j = 0; j < 4; ++j) o[j] = f2bf(v[j]);
    *(u16x4*)(xb + i * 4) = o;       // 8 B/lane, lanes contiguous
  }
}

// ------- kernel 2: p = xb @ bb^T, R5-exact structure + fused sq -------
__global__ __launch_bounds__(256) void k_projb(
    const unsigned short* __restrict__ xb,
    const unsigned short* __restrict__ bb,
    unsigned short* __restrict__ p,
    float* __restrict__ sq) {
  __shared__ __align__(16) unsigned short smA[3][128 * 32];
  __shared__ __align__(16) unsigned short smB[3][128 * 32];
  const int tid = threadIdx.x;
  const int w = tid >> 6, l = tid & 63;
  // 1536 blocks, 192/XCD; nt fastest -> 6 consecutive wgs share the A m-tile
  const int wg = ((blockIdx.x & 7) * 192) + (blockIdx.x >> 3);
  const int nt = wg % 6, mt = wg / 6;
  const long m0 = (long)mt * 128, n0 = (long)nt * 128;
  const int wr = (w >> 1) * 64, wc = (w & 1) * 64;

  const int srow = tid >> 2;
  const int scol = ((tid & 3) ^ ((srow >> 1) & 3)) * 8; // pre-swizzled source
  const unsigned short* gA = xb + (m0 + srow) * (long)NL + scol;
  const unsigned short* gB = bb + (n0 + srow) * (long)NL + scol;

  const int qh = l >> 4, lr = l & 15;
  const int aoff = (wr + lr) * 64 + ((qh ^ ((lr >> 1) & 3)) << 4);
  const int boff = (wc + lr) * 64 + ((qh ^ ((lr >> 1) & 3)) << 4);

  f32x4 acc[4][4] = {};

#define STAGEP(k0, buf)                                                      \
  {                                                                          \
    char* da_ = (char*)&smA[buf][0] + w * 1024;                              \
    char* db_ = (char*)&smB[buf][0] + w * 1024;                              \
    gload_lds16(gA + (k0), da_);                                             \
    gload_lds16(gA + (k0) + 64 * NL, da_ + 4096);                            \
    gload_lds16(gB + (k0), db_);                                             \
    gload_lds16(gB + (k0) + 64 * NL, db_ + 4096);                            \
  }
#define COMPUTEP(buf)                                                        \
  {                                                                          \
    const char* A_ = (const char*)&smA[buf][0];                              \
    const char* B_ = (const char*)&smB[buf][0];                              \
    bf16x8 fa[4], fb[4];                                                     \
    _Pragma("unroll")                                                        \
    for (int m = 0; m < 4; ++m)                                              \
      fa[m] = *(const bf16x8*)(A_ + aoff + m * 1024);                        \
    _Pragma("unroll")                                                        \
    for (int n = 0; n < 4; ++n)                                              \
      fb[n] = *(const bf16x8*)(B_ + boff + n * 1024);                        \
    _Pragma("unroll")                                                        \
    for (int m = 0; m < 4; ++m)                                              \
      _Pragma("unroll")                                                      \
      for (int n = 0; n < 4; ++n)                                            \
        acc[m][n] = __builtin_amdgcn_mfma_f32_16x16x32_bf16(fa[m], fb[n],    \
                                                            acc[m][n], 0, 0, 0); \
  }

  STAGEP(0, 0)
  STAGEP(32, 1)
  int cur = 0, nxt2 = 2;
#pragma unroll 1
  for (int kt = 0; kt < 23; ++kt) {
    asm volatile("s_waitcnt vmcnt(4)" ::: "memory");
    __builtin_amdgcn_s_barrier();
    MEMFENCE;
    if (kt < 22) STAGEP((kt + 2) * 32, nxt2)
    COMPUTEP(cur)
    cur = (cur == 2) ? 0 : cur + 1;
    nxt2 = (nxt2 == 2) ? 0 : nxt2 + 1;
  }
  asm volatile("s_waitcnt vmcnt(0)" ::: "memory");
  __builtin_amdgcn_s_barrier();
  MEMFENCE;
  COMPUTEP(cur)
#undef STAGEP
#undef COMPUTEP

  // epilogue: C/D layout col = lane&15, row = (lane>>4)*4 + reg.
  // Writes p (bf16); accumulates sq[row] from the ROUNDED values (16 lanes
  // lr=0..15 hold the row's 4 cols each -> 4-step shuffle reduce, one
  // atomicAdd per (row, block) by lane lr==0 of each qh group.
#pragma unroll
  for (int m = 0; m < 4; ++m) {
    const long rbase = m0 + wr + m * 16 + qh * 4;
#pragma unroll
    for (int r = 0; r < 4; ++r) {
      const long row = rbase + r;
      float s = 0.f;
#pragma unroll
      for (int n = 0; n < 4; ++n) {
        const unsigned short us = f2bf(acc[m][n][r]);
        p[row * NL + (n0 + wc + n * 16 + lr)] = us;
        const float f = __builtin_bit_cast(float, ((unsigned)us) << 16);
        s += f * f;
      }
      s += __shfl_xor(s, 1, 64);
      s += __shfl_xor(s, 2, 64);
      s += __shfl_xor(s, 4, 64);
      s += __shfl_xor(s, 8, 64);
      if (lr == 0) atomicAdd(sq + row, s);
    }
  }
}

// ------- kernel 4: per-batch gram (R5-exact) + epilogue -------
__global__ __launch_bounds__(256) void k_gram(const unsigned short* __restrict__ p,
                                              const float* __restrict__ sq,
                                              float* __restrict__ out) {
  __shared__ __align__(16) unsigned short smA[3][128 * 32];
  __shared__ __align__(16) unsigned short smB[3][128 * 32];
  const int tid = threadIdx.x;
  const int w = tid >> 6, l = tid & 63;
  const int wg = ((blockIdx.x & 7) * 128) + (blockIdx.x >> 3);
  const int batch = wg >> 4, tile = wg & 15;
  const int mt = tile >> 2, nt = tile & 3;
  const unsigned short* pb = p + (long)batch * NS * NL;
  const long m0 = (long)mt * 128, n0 = (long)nt * 128;
  const int wr = (w >> 1) * 64, wc = (w & 1) * 64;

  const int srow = tid >> 2;
  const int scol = ((tid & 3) ^ ((srow >> 1) & 3)) * 8;
  const unsigned short* gA = pb + (m0 + srow) * (long)NL + scol;
  const unsigned short* gB = pb + (n0 + srow) * (long)NL + scol;

  const int qh = l >> 4, lr = l & 15;
  const int aoff = (wr + lr) * 64 + ((qh ^ ((lr >> 1) & 3)) << 4);
  const int boff = (wc + lr) * 64 + ((qh ^ ((lr >> 1) & 3)) << 4);

  f32x4 acc[4][4] = {};

#define STAGE2(k0, buf)                                                      \
  {                                                                          \
    char* da_ = (char*)&smA[buf][0] + w * 1024;                              \
    char* db_ = (char*)&smB[buf][0] + w * 1024;                              \
    gload_lds16(gA + (k0), da_);                                             \
    gload_lds16(gA + (k0) + 64 * NL, da_ + 4096);                            \
    gload_lds16(gB + (k0), db_);                                             \
    gload_lds16(gB + (k0) + 64 * NL, db_ + 4096);                            \
  }
#define COMPUTE2(buf)                                                        \
  {                                                                          \
    const char* A_ = (const char*)&smA[buf][0];                              \
    const char* B_ = (const char*)&smB[buf][0];                              \
    bf16x8 fa[4], fb[4];                                                     \
    _Pragma("unroll")                                                        \
    for (int m = 0; m < 4; ++m)                                              \
      fa[m] = *(const bf16x8*)(A_ + aoff + m * 1024);                        \
    _Pragma("unroll")                                                        \
    for (int n = 0; n < 4; ++n)                                              \
      fb[n] = *(const bf16x8*)(B_ + boff + n * 1024);                        \
    _Pragma("unroll")                                                        \
    for (int m = 0; m < 4; ++m)                                              \
      _Pragma("unroll")                                                      \
      for (int n = 0; n < 4; ++n)                                            \
        acc[m][n] = __builtin_amdgcn_mfma_f32_16x16x32_bf16(fa[m], fb[n],    \
                                                            acc[m][n], 0, 0, 0); \
  }

  STAGE2(0, 0)
  STAGE2(32, 1)
  int cur = 0, nxt2 = 2;
#pragma unroll 1
  for (int kt = 0; kt < 23; ++kt) {
    asm volatile("s_waitcnt vmcnt(4)" ::: "memory");
    __builtin_amdgcn_s_barrier();
    MEMFENCE;
    if (kt < 22) STAGE2((kt + 2) * 32, nxt2)
    COMPUTE2(cur)
    cur = (cur == 2) ? 0 : cur + 1;
    nxt2 = (nxt2 == 2) ? 0 : nxt2 + 1;
  }
  asm volatile("s_waitcnt vmcnt(0)" ::: "memory");
  __builtin_amdgcn_s_barrier();
  MEMFENCE;
  COMPUTE2(cur)
#undef STAGE2
#undef COMPUTE2

  const float* sqb = sq + batch * NS;
  float* outb = out + (long)batch * NS * NS;
  float sqc[4];
#pragma unroll
  for (int n = 0; n < 4; ++n) sqc[n] = sqb[n0 + wc + n * 16 + lr];
#pragma unroll
  for (int m = 0; m < 4; ++m) {
#pragma unroll
    for (int r = 0; r < 4; ++r) {
      const long row = m0 + wr + m * 16 + qh * 4 + r;
      const float sr = sqb[row];
#pragma unroll
      for (int n = 0; n < 4; ++n) {
        const long col = n0 + wc + n * 16 + lr;
        outb[row * NS + col] = sr + sqc[n] - 2.0f * acc[m][n][r];
      }
    }
  }
}

extern "C" void kernel_launch(void* const* d_in, const int* in_sizes, int n_in,
                              void* d_out, int out_size, void* d_ws, size_t ws_size,
                              hipStream_t stream) {
  (void)in_sizes; (void)n_in; (void)out_size; (void)ws_size;
  const float* x = (const float*)d_in[0]; // [B,S,L] fp32
  const float* b = (const float*)d_in[1]; // [L,L] fp32
  float* out = (float*)d_out;             // [B,S,S] fp32
  char* ws = (char*)d_ws;
  unsigned short* bb = (unsigned short*)ws;              //  1,179,648 B
  float* sq          = (float*)(ws + 1179648);           //    131,072 B
  unsigned short* p  = (unsigned short*)(ws + 1310720);  // 50,331,648 B
  unsigned short* xb = (unsigned short*)(ws + 51642368); // 50,331,648 B

  k_cvt_b<<<576, 256, 0, stream>>>(b, bb);
  k_cvt_x<<<2048, 256, 0, stream>>>(x, xb, sq);    // also zeroes sq
  k_projb<<<1536, 256, 0, stream>>>(xb, bb, p, sq); // 256 m x 6 n, fused sq
  k_gram <<<1024, 256, 0, stream>>>(p, sq, out);    // 64 batches x 16 tiles
}

// Round 9
// 131.985 us; speedup vs baseline: 1.0408x; 1.0306x over previous
//
#include <hip/hip_runtime.h>
#include <hip/hip_bf16.h>

// out[b,s,t] = ||B(x_s - x_t)||^2 = sq[s] + sq[t] - 2*gram[s,t],  p = x @ B^T
// Round 9: projb = BM128 x BN256, 512 threads (8 waves), A 3-buf + B 2-buf
// (56 KB -> 2 blocks/CU, 16 waves/CU), counted vmcnt(1) schedule.
// sq via 12-plane partial stores (no atomics) + k_sqsum. gram = R5-proven.

using bf16x8 = __attribute__((ext_vector_type(8))) __bf16;
using f32x4  = __attribute__((ext_vector_type(4))) float;
using fl4    = __attribute__((ext_vector_type(4))) float;
using u16x4  = __attribute__((ext_vector_type(4))) unsigned short;
using u16x8  = __attribute__((ext_vector_type(8))) unsigned short;

#define NB 64
#define NS 512
#define NL 768
#define NM (NB * NS)

__device__ __forceinline__ unsigned short f2bf(float f) {
  unsigned u = __builtin_bit_cast(unsigned, f);
  u += 0x7FFFu + ((u >> 16) & 1u); // RNE
  return (unsigned short)(u >> 16);
}

__device__ __forceinline__ void gload_lds16(const void* g, void* l) {
  __builtin_amdgcn_global_load_lds(
      (const __attribute__((address_space(1))) void*)g,
      (__attribute__((address_space(3))) void*)l, 16, 0, 0);
}

#define MEMFENCE asm volatile("" ::: "memory")

// ---------------- kernel 1: convert b (L x L fp32) -> bb bf16 ----------------
__global__ __launch_bounds__(256) void k_cvt_b(const float* __restrict__ b,
                                               unsigned short* __restrict__ bb) {
  const long t = (long)blockIdx.x * 256 + threadIdx.x;
  fl4 v = *(const fl4*)(b + t * 4);
  u16x4 o;
#pragma unroll
  for (int j = 0; j < 4; ++j) o[j] = f2bf(v[j]);
  *(u16x4*)(bb + t * 4) = o;
}

// ------------- kernel 1b: convert x -> xb bf16, 8 floats/thread -------------
__global__ __launch_bounds__(256) void k_cvt_x(const float* __restrict__ x,
                                               unsigned short* __restrict__ xb) {
  const long n8 = (long)NM * NL / 8;
  const long stride = (long)gridDim.x * 256;
  for (long i = (long)blockIdx.x * 256 + threadIdx.x; i < n8; i += stride) {
    fl4 v0 = *(const fl4*)(x + i * 8);
    fl4 v1 = *(const fl4*)(x + i * 8 + 4);
    u16x8 o;
#pragma unroll
    for (int j = 0; j < 4; ++j) { o[j] = f2bf(v0[j]); o[j + 4] = f2bf(v1[j]); }
    *(u16x8*)(xb + i * 8) = o; // 16 B/lane, lanes contiguous
  }
}

// ------ kernel 2: p = xb @ bb^T. BM=128 BN=256, 8 waves, A3/B2 buffers ------
__global__ __launch_bounds__(512) void k_projb(
    const unsigned short* __restrict__ xb,
    const unsigned short* __restrict__ bb,
    unsigned short* __restrict__ p,
    float* __restrict__ spart) {
  __shared__ __align__(16) unsigned short smA[3][128 * 32]; // 3 x 8 KB
  __shared__ __align__(16) unsigned short smB[2][256 * 32]; // 2 x 16 KB
  const int tid = threadIdx.x;
  const int w = tid >> 6, l = tid & 63;
  // 768 blocks, 96/XCD; nt fastest: 3 consecutive wgs share the A m-tile
  const int wg = ((blockIdx.x & 7) * 96) + (blockIdx.x >> 3);
  const int nt = wg % 3, mt = wg / 3;
  const long m0 = (long)mt * 128, n0 = (long)nt * 256;
  const int wr = (w >> 2) * 64, wc = (w & 3) * 64;

  // A staging (1 call/wave): rows w*16 + l/4, chunk l&3, source pre-swizzled
  const int arow = (w << 4) + (l >> 2);
  const int acol = ((l & 3) ^ ((arow >> 1) & 3)) * 8;
  const unsigned short* gA = xb + (m0 + arow) * (long)NL + acol;
  // B staging (2 calls/wave): rows w*32 + {0,16} + l/4
  const int brow = (w << 5) + (l >> 2);
  const int bcol = ((l & 3) ^ ((brow >> 1) & 3)) * 8; // (brow+16) gives same
  const unsigned short* gB = bb + (n0 + brow) * (long)NL + bcol;

  const int qh = l >> 4, lr = l & 15;
  const int swz = ((qh ^ ((lr >> 1) & 3)) << 4);
  const int aoff = (wr + lr) * 64 + swz;
  const int boff = (wc + lr) * 64 + swz;

  f32x4 acc[4][4] = {};

#define STAGE_B(k0, buf)                                                     \
  {                                                                          \
    char* db_ = (char*)&smB[buf][0] + w * 2048;                              \
    gload_lds16(gB + (k0), db_);                                             \
    gload_lds16(gB + (k0) + 16 * NL, db_ + 1024);                            \
  }
#define STAGE_A(k0, buf)                                                     \
  {                                                                          \
    char* da_ = (char*)&smA[buf][0] + w * 1024;                              \
    gload_lds16(gA + (k0), da_);                                             \
  }
#define COMPUTEP(bA, bB)                                                     \
  {                                                                          \
    const char* A_ = (const char*)&smA[bA][0];                               \
    const char* B_ = (const char*)&smB[bB][0];                               \
    bf16x8 fa[4], fb[4];                                                     \
    _Pragma("unroll")                                                        \
    for (int m = 0; m < 4; ++m)                                              \
      fa[m] = *(const bf16x8*)(A_ + aoff + m * 1024);                        \
    _Pragma("unroll")                                                        \
    for (int n = 0; n < 4; ++n)                                              \
      fb[n] = *(const bf16x8*)(B_ + boff + n * 1024);                        \
    _Pragma("unroll")                                                        \
    for (int m = 0; m < 4; ++m)                                              \
      _Pragma("unroll")                                                      \
      for (int n = 0; n < 4; ++n)                                            \
        acc[m][n] = __builtin_amdgcn_mfma_f32_16x16x32_bf16(fa[m], fb[n],    \
                                                            acc[m][n], 0, 0, 0); \
  }

  // prologue: B(0), A(0), A(1)  -> outstanding [B0,B0,A0,A1]
  STAGE_B(0, 0)
  STAGE_A(0, 0)
  STAGE_A(32, 1)
  int bufA = 0;
#pragma unroll 1
  for (int kt = 0; kt < 23; ++kt) {
    // retire oldest 3 = {A(t) or prologue B0/A0, B(t)}; leave A(t+1) in flight
    asm volatile("s_waitcnt vmcnt(1)" ::: "memory");
    __builtin_amdgcn_s_barrier();
    MEMFENCE;
    STAGE_B((kt + 1) * 32, (kt + 1) & 1)     // B one-ahead (2-buf)
    if (kt < 22) {
      const int bA2 = (bufA >= 1) ? bufA - 1 : bufA + 2; // (bufA+2)%3
      STAGE_A((kt + 2) * 32, bA2)            // A two-ahead (3-buf)
    }
    COMPUTEP(bufA, kt & 1)
    bufA = (bufA == 2) ? 0 : bufA + 1;
  }
  asm volatile("s_waitcnt vmcnt(0)" ::: "memory");
  __builtin_amdgcn_s_barrier();
  MEMFENCE;
  COMPUTEP(bufA, 1) // kt=23: bufA=2, bufB=23&1=1
#undef STAGE_B
#undef STAGE_A
#undef COMPUTEP

  // epilogue: C/D layout col = lane&15, row = (lane>>4)*4 + reg.
  // p-write + per-row partial sums into plane j = nt*4 + (w&3) (no atomics).
#pragma unroll
  for (int m = 0; m < 4; ++m) {
    const long rbase = m0 + wr + m * 16 + qh * 4;
#pragma unroll
    for (int r = 0; r < 4; ++r) {
      const long row = rbase + r;
      float s = 0.f;
#pragma unroll
      for (int n = 0; n < 4; ++n) {
        const unsigned short us = f2bf(acc[m][n][r]);
        p[row * NL + (n0 + wc + n * 16 + lr)] = us;
        const float f = __builtin_bit_cast(float, ((unsigned)us) << 16);
        s += f * f;
      }
      s += __shfl_xor(s, 1, 64);
      s += __shfl_xor(s, 2, 64);
      s += __shfl_xor(s, 4, 64);
      s += __shfl_xor(s, 8, 64);
      if (lr == 0) spart[(long)(nt * 4 + (w & 3)) * NM + row] = s;
    }
  }
}

// ---------------- kernel 2b: sq[row] = sum of 12 partial planes ----------------
__global__ __launch_bounds__(256) void k_sqsum(const float* __restrict__ spart,
                                               float* __restrict__ sq) {
  const int row = blockIdx.x * 256 + threadIdx.x;
  float s = 0.f;
#pragma unroll
  for (int j = 0; j < 12; ++j) s += spart[(long)j * NM + row];
  sq[row] = s;
}

// ------- kernel 4: per-batch gram (R5-exact) + epilogue -------
__global__ __launch_bounds__(256) void k_gram(const unsigned short* __restrict__ p,
                                              const float* __restrict__ sq,
                                              float* __restrict__ out) {
  __shared__ __align__(16) unsigned short smA[3][128 * 32];
  __shared__ __align__(16) unsigned short smB[3][128 * 32];
  const int tid = threadIdx.x;
  const int w = tid >> 6, l = tid & 63;
  const int wg = ((blockIdx.x & 7) * 128) + (blockIdx.x >> 3);
  const int batch = wg >> 4, tile = wg & 15;
  const int mt = tile >> 2, nt = tile & 3;
  const unsigned short* pb = p + (long)batch * NS * NL;
  const long m0 = (long)mt * 128, n0 = (long)nt * 128;
  const int wr = (w >> 1) * 64, wc = (w & 1) * 64;

  const int srow = tid >> 2;
  const int scol = ((tid & 3) ^ ((srow >> 1) & 3)) * 8;
  const unsigned short* gA = pb + (m0 + srow) * (long)NL + scol;
  const unsigned short* gB = pb + (n0 + srow) * (long)NL + scol;

  const int qh = l >> 4, lr = l & 15;
  const int aoff = (wr + lr) * 64 + ((qh ^ ((lr >> 1) & 3)) << 4);
  const int boff = (wc + lr) * 64 + ((qh ^ ((lr >> 1) & 3)) << 4);

  f32x4 acc[4][4] = {};

#define STAGE2(k0, buf)                                                      \
  {                                                                          \
    char* da_ = (char*)&smA[buf][0] + w * 1024;                              \
    char* db_ = (char*)&smB[buf][0] + w * 1024;                              \
    gload_lds16(gA + (k0), da_);                                             \
    gload_lds16(gA + (k0) + 64 * NL, da_ + 4096);                            \
    gload_lds16(gB + (k0), db_);                                             \
    gload_lds16(gB + (k0) + 64 * NL, db_ + 4096);                            \
  }
#define COMPUTE2(buf)                                                        \
  {                                                                          \
    const char* A_ = (const char*)&smA[buf][0];                              \
    const char* B_ = (const char*)&smB[buf][0];                              \
    bf16x8 fa[4], fb[4];                                                     \
    _Pragma("unroll")                                                        \
    for (int m = 0; m < 4; ++m)                                              \
      fa[m] = *(const bf16x8*)(A_ + aoff + m * 1024);                        \
    _Pragma("unroll")                                                        \
    for (int n = 0; n < 4; ++n)                                              \
      fb[n] = *(const bf16x8*)(B_ + boff + n * 1024);                        \
    _Pragma("unroll")                                                        \
    for (int m = 0; m < 4; ++m)                                              \
      _Pragma("unroll")                                                      \
      for (int n = 0; n < 4; ++n)                                            \
        acc[m][n] = __builtin_amdgcn_mfma_f32_16x16x32_bf16(fa[m], fb[n],    \
                                                            acc[m][n], 0, 0, 0); \
  }

  STAGE2(0, 0)
  STAGE2(32, 1)
  int cur = 0, nxt2 = 2;
#pragma unroll 1
  for (int kt = 0; kt < 23; ++kt) {
    asm volatile("s_waitcnt vmcnt(4)" ::: "memory");
    __builtin_amdgcn_s_barrier();
    MEMFENCE;
    if (kt < 22) STAGE2((kt + 2) * 32, nxt2)
    COMPUTE2(cur)
    cur = (cur == 2) ? 0 : cur + 1;
    nxt2 = (nxt2 == 2) ? 0 : nxt2 + 1;
  }
  asm volatile("s_waitcnt vmcnt(0)" ::: "memory");
  __builtin_amdgcn_s_barrier();
  MEMFENCE;
  COMPUTE2(cur)
#undef STAGE2
#undef COMPUTE2

  const float* sqb = sq + batch * NS;
  float* outb = out + (long)batch * NS * NS;
  float sqc[4];
#pragma unroll
  for (int n = 0; n < 4; ++n) sqc[n] = sqb[n0 + wc + n * 16 + lr];
#pragma unroll
  for (int m = 0; m < 4; ++m) {
#pragma unroll
    for (int r = 0; r < 4; ++r) {
      const long row = m0 + wr + m * 16 + qh * 4 + r;
      const float sr = sqb[row];
#pragma unroll
      for (int n = 0; n < 4; ++n) {
        const long col = n0 + wc + n * 16 + lr;
        outb[row * NS + col] = sr + sqc[n] - 2.0f * acc[m][n][r];
      }
    }
  }
}

extern "C" void kernel_launch(void* const* d_in, const int* in_sizes, int n_in,
                              void* d_out, int out_size, void* d_ws, size_t ws_size,
                              hipStream_t stream) {
  (void)in_sizes; (void)n_in; (void)out_size; (void)ws_size;
  const float* x = (const float*)d_in[0]; // [B,S,L] fp32
  const float* b = (const float*)d_in[1]; // [L,L] fp32
  float* out = (float*)d_out;             // [B,S,S] fp32
  char* ws = (char*)d_ws;
  // ws layout (~98.8 MiB):
  unsigned short* bb = (unsigned short*)ws;              //  1,179,648 B
  float* sq          = (float*)(ws + 1179648);           //    131,072 B
  float* spart       = (float*)(ws + 1310720);           //  1,572,864 B (12 planes)
  unsigned short* p  = (unsigned short*)(ws + 2883584);  // 50,331,648 B
  unsigned short* xb = (unsigned short*)(ws + 53215232); // 50,331,648 B

  k_cvt_b<<<576, 256, 0, stream>>>(b, bb);
  k_cvt_x<<<2048, 256, 0, stream>>>(x, xb);
  k_projb<<<768, 512, 0, stream>>>(xb, bb, p, spart); // 256 m x 3 n
  k_sqsum<<<128, 256, 0, stream>>>(spart, sq);
  k_gram <<<1024, 256, 0, stream>>>(p, sq, out);      // 64 batches x 16 tiles
}

// Round 10
// 130.486 us; speedup vs baseline: 1.0527x; 1.0115x over previous
//
#include <hip/hip_runtime.h>
#include <hip/hip_bf16.h>

// out[b,s,t] = ||B(x_s - x_t)||^2 = sq[s] + sq[t] - 2*gram[s,t],  p = x @ B^T
// Round 10: assembly of measured-best parts, no new structure.
//  cvt_b (2us) + cvt_x R6-exact 4-float coalesced (~25us) +
//  projb R5-EXACT (64.5us measured; 128^2, 3-buf, vmcnt(4), no fused sq) +
//  k_sq R1-exact (8us) + gram R5-exact (3-buf counted).

using bf16x8 = __attribute__((ext_vector_type(8))) __bf16;
using f32x4  = __attribute__((ext_vector_type(4))) float;
using fl4    = __attribute__((ext_vector_type(4))) float;
using u16x4  = __attribute__((ext_vector_type(4))) unsigned short;

#define NB 64
#define NS 512
#define NL 768
#define NM (NB * NS)

__device__ __forceinline__ unsigned short f2bf(float f) {
  unsigned u = __builtin_bit_cast(unsigned, f);
  u += 0x7FFFu + ((u >> 16) & 1u); // RNE
  return (unsigned short)(u >> 16);
}

__device__ __forceinline__ void gload_lds16(const void* g, void* l) {
  __builtin_amdgcn_global_load_lds(
      (const __attribute__((address_space(1))) void*)g,
      (__attribute__((address_space(3))) void*)l, 16, 0, 0);
}

#define MEMFENCE asm volatile("" ::: "memory")

// ---------------- kernel 1: convert b (L x L fp32) -> bb bf16 ----------------
__global__ __launch_bounds__(256) void k_cvt_b(const float* __restrict__ b,
                                               unsigned short* __restrict__ bb) {
  const long t = (long)blockIdx.x * 256 + threadIdx.x;
  fl4 v = *(const fl4*)(b + t * 4);
  u16x4 o;
#pragma unroll
  for (int j = 0; j < 4; ++j) o[j] = f2bf(v[j]);
  *(u16x4*)(bb + t * 4) = o;
}

// ------- kernel 1b: convert x -> xb bf16 (R6-exact: 16 B/lane contiguous) ----
__global__ __launch_bounds__(256) void k_cvt_x(const float* __restrict__ x,
                                               unsigned short* __restrict__ xb) {
  const long n4 = (long)NM * NL / 4;
  const long stride = (long)gridDim.x * 256;
  for (long i = (long)blockIdx.x * 256 + threadIdx.x; i < n4; i += stride) {
    fl4 v = *(const fl4*)(x + i * 4); // 16 B/lane, lanes contiguous
    u16x4 o;
#pragma unroll
    for (int j = 0; j < 4; ++j) o[j] = f2bf(v[j]);
    *(u16x4*)(xb + i * 4) = o;       // 8 B/lane, lanes contiguous
  }
}

// ------- kernel 2: p = xb @ bb^T  (R5-EXACT: 128^2, 3-buf, vmcnt(4)) -------
__global__ __launch_bounds__(256) void k_projb(
    const unsigned short* __restrict__ xb,
    const unsigned short* __restrict__ bb,
    unsigned short* __restrict__ p) {
  __shared__ __align__(16) unsigned short smA[3][128 * 32];
  __shared__ __align__(16) unsigned short smB[3][128 * 32];
  const int tid = threadIdx.x;
  const int w = tid >> 6, l = tid & 63;
  // 1536 blocks, 192/XCD; nt fastest -> 6 consecutive wgs share the A m-tile
  const int wg = ((blockIdx.x & 7) * 192) + (blockIdx.x >> 3);
  const int nt = wg % 6, mt = wg / 6;
  const long m0 = (long)mt * 128, n0 = (long)nt * 128;
  const int wr = (w >> 1) * 64, wc = (w & 1) * 64;

  const int srow = tid >> 2;
  const int scol = ((tid & 3) ^ ((srow >> 1) & 3)) * 8; // pre-swizzled source
  const unsigned short* gA = xb + (m0 + srow) * (long)NL + scol;
  const unsigned short* gB = bb + (n0 + srow) * (long)NL + scol;

  const int qh = l >> 4, lr = l & 15;
  const int aoff = (wr + lr) * 64 + ((qh ^ ((lr >> 1) & 3)) << 4);
  const int boff = (wc + lr) * 64 + ((qh ^ ((lr >> 1) & 3)) << 4);

  f32x4 acc[4][4] = {};

#define STAGEP(k0, buf)                                                      \
  {                                                                          \
    char* da_ = (char*)&smA[buf][0] + w * 1024;                              \
    char* db_ = (char*)&smB[buf][0] + w * 1024;                              \
    gload_lds16(gA + (k0), da_);                                             \
    gload_lds16(gA + (k0) + 64 * NL, da_ + 4096);                            \
    gload_lds16(gB + (k0), db_);                                             \
    gload_lds16(gB + (k0) + 64 * NL, db_ + 4096);                            \
  }
#define COMPUTEP(buf)                                                        \
  {                                                                          \
    const char* A_ = (const char*)&smA[buf][0];                              \
    const char* B_ = (const char*)&smB[buf][0];                              \
    bf16x8 fa[4], fb[4];                                                     \
    _Pragma("unroll")                                                        \
    for (int m = 0; m < 4; ++m)                                              \
      fa[m] = *(const bf16x8*)(A_ + aoff + m * 1024);                        \
    _Pragma("unroll")                                                        \
    for (int n = 0; n < 4; ++n)                                              \
      fb[n] = *(const bf16x8*)(B_ + boff + n * 1024);                        \
    _Pragma("unroll")                                                        \
    for (int m = 0; m < 4; ++m)                                              \
      _Pragma("unroll")                                                      \
      for (int n = 0; n < 4; ++n)                                            \
        acc[m][n] = __builtin_amdgcn_mfma_f32_16x16x32_bf16(fa[m], fb[n],    \
                                                            acc[m][n], 0, 0, 0); \
  }

  STAGEP(0, 0)
  STAGEP(32, 1)
  int cur = 0, nxt2 = 2;
#pragma unroll 1
  for (int kt = 0; kt < 23; ++kt) {
    asm volatile("s_waitcnt vmcnt(4)" ::: "memory");
    __builtin_amdgcn_s_barrier();
    MEMFENCE;
    if (kt < 22) STAGEP((kt + 2) * 32, nxt2)
    COMPUTEP(cur)
    cur = (cur == 2) ? 0 : cur + 1;
    nxt2 = (nxt2 == 2) ? 0 : nxt2 + 1;
  }
  asm volatile("s_waitcnt vmcnt(0)" ::: "memory");
  __builtin_amdgcn_s_barrier();
  MEMFENCE;
  COMPUTEP(cur)
#undef STAGEP
#undef COMPUTEP

  // epilogue: C/D layout col = lane&15, row = (lane>>4)*4 + reg
#pragma unroll
  for (int m = 0; m < 4; ++m) {
    const long rbase = m0 + wr + m * 16 + qh * 4;
#pragma unroll
    for (int n = 0; n < 4; ++n) {
      const long col = n0 + wc + n * 16 + lr;
#pragma unroll
      for (int r = 0; r < 4; ++r)
        p[(rbase + r) * NL + col] = f2bf(acc[m][n][r]);
    }
  }
}

// ---------------- kernel 3: sq[i] = sum_g p[i,g]^2 (R1-exact) ----------------
__global__ __launch_bounds__(256) void k_sq(const unsigned short* __restrict__ p,
                                            float* __restrict__ sq) {
  const int row = blockIdx.x * 4 + (threadIdx.x >> 6);
  const int l = threadIdx.x & 63;
  const unsigned short* pr = p + (long)row * NL;
  float s = 0.f;
#pragma unroll
  for (int c = 0; c < 3; ++c) {
    u16x4 v = *(const u16x4*)(pr + (c * 64 + l) * 4);
#pragma unroll
    for (int j = 0; j < 4; ++j) {
      float f = __builtin_bit_cast(float, ((unsigned)v[j]) << 16);
      s += f * f;
    }
  }
#pragma unroll
  for (int d = 32; d >= 1; d >>= 1) s += __shfl_xor(s, d, 64);
  if (l == 0) sq[row] = s;
}

// ------- kernel 4: per-batch gram (R5-exact) + epilogue -------
__global__ __launch_bounds__(256) void k_gram(const unsigned short* __restrict__ p,
                                              const float* __restrict__ sq,
                                              float* __restrict__ out) {
  __shared__ __align__(16) unsigned short smA[3][128 * 32];
  __shared__ __align__(16) unsigned short smB[3][128 * 32];
  const int tid = threadIdx.x;
  const int w = tid >> 6, l = tid & 63;
  const int wg = ((blockIdx.x & 7) * 128) + (blockIdx.x >> 3);
  const int batch = wg >> 4, tile = wg & 15;
  const int mt = tile >> 2, nt = tile & 3;
  const unsigned short* pb = p + (long)batch * NS * NL;
  const long m0 = (long)mt * 128, n0 = (long)nt * 128;
  const int wr = (w >> 1) * 64, wc = (w & 1) * 64;

  const int srow = tid >> 2;
  const int scol = ((tid & 3) ^ ((srow >> 1) & 3)) * 8;
  const unsigned short* gA = pb + (m0 + srow) * (long)NL + scol;
  const unsigned short* gB = pb + (n0 + srow) * (long)NL + scol;

  const int qh = l >> 4, lr = l & 15;
  const int aoff = (wr + lr) * 64 + ((qh ^ ((lr >> 1) & 3)) << 4);
  const int boff = (wc + lr) * 64 + ((qh ^ ((lr >> 1) & 3)) << 4);

  f32x4 acc[4][4] = {};

#define STAGE2(k0, buf)                                                      \
  {                                                                          \
    char* da_ = (char*)&smA[buf][0] + w * 1024;                              \
    char* db_ = (char*)&smB[buf][0] + w * 1024;                              \
    gload_lds16(gA + (k0), da_);                                             \
    gload_lds16(gA + (k0) + 64 * NL, da_ + 4096);                            \
    gload_lds16(gB + (k0), db_);                                             \
    gload_lds16(gB + (k0) + 64 * NL, db_ + 4096);                            \
  }
#define COMPUTE2(buf)                                                        \
  {                                                                          \
    const char* A_ = (const char*)&smA[buf][0];                              \
    const char* B_ = (const char*)&smB[buf][0];                              \
    bf16x8 fa[4], fb[4];                                                     \
    _Pragma("unroll")                                                        \
    for (int m = 0; m < 4; ++m)                                              \
      fa[m] = *(const bf16x8*)(A_ + aoff + m * 1024);                        \
    _Pragma("unroll")                                                        \
    for (int n = 0; n < 4; ++n)                                              \
      fb[n] = *(const bf16x8*)(B_ + boff + n * 1024);                        \
    _Pragma("unroll")                                                        \
    for (int m = 0; m < 4; ++m)                                              \
      _Pragma("unroll")                                                      \
      for (int n = 0; n < 4; ++n)                                            \
        acc[m][n] = __builtin_amdgcn_mfma_f32_16x16x32_bf16(fa[m], fb[n],    \
                                                            acc[m][n], 0, 0, 0); \
  }

  STAGE2(0, 0)
  STAGE2(32, 1)
  int cur = 0, nxt2 = 2;
#pragma unroll 1
  for (int kt = 0; kt < 23; ++kt) {
    asm volatile("s_waitcnt vmcnt(4)" ::: "memory");
    __builtin_amdgcn_s_barrier();
    MEMFENCE;
    if (kt < 22) STAGE2((kt + 2) * 32, nxt2)
    COMPUTE2(cur)
    cur = (cur == 2) ? 0 : cur + 1;
    nxt2 = (nxt2 == 2) ? 0 : nxt2 + 1;
  }
  asm volatile("s_waitcnt vmcnt(0)" ::: "memory");
  __builtin_amdgcn_s_barrier();
  MEMFENCE;
  COMPUTE2(cur)
#undef STAGE2
#undef COMPUTE2

  const float* sqb = sq + batch * NS;
  float* outb = out + (long)batch * NS * NS;
  float sqc[4];
#pragma unroll
  for (int n = 0; n < 4; ++n) sqc[n] = sqb[n0 + wc + n * 16 + lr];
#pragma unroll
  for (int m = 0; m < 4; ++m) {
#pragma unroll
    for (int r = 0; r < 4; ++r) {
      const long row = m0 + wr + m * 16 + qh * 4 + r;
      const float sr = sqb[row];
#pragma unroll
      for (int n = 0; n < 4; ++n) {
        const long col = n0 + wc + n * 16 + lr;
        outb[row * NS + col] = sr + sqc[n] - 2.0f * acc[m][n][r];
      }
    }
  }
}

extern "C" void kernel_launch(void* const* d_in, const int* in_sizes, int n_in,
                              void* d_out, int out_size, void* d_ws, size_t ws_size,
                              hipStream_t stream) {
  (void)in_sizes; (void)n_in; (void)out_size; (void)ws_size;
  const float* x = (const float*)d_in[0]; // [B,S,L] fp32
  const float* b = (const float*)d_in[1]; // [L,L] fp32
  float* out = (float*)d_out;             // [B,S,S] fp32
  char* ws = (char*)d_ws;
  unsigned short* bb = (unsigned short*)ws;              //  1,179,648 B
  float* sq          = (float*)(ws + 1179648);           //    131,072 B
  unsigned short* p  = (unsigned short*)(ws + 1310720);  // 50,331,648 B
  unsigned short* xb = (unsigned short*)(ws + 51642368); // 50,331,648 B

  k_cvt_b<<<576, 256, 0, stream>>>(b, bb);
  k_cvt_x<<<2048, 256, 0, stream>>>(x, xb);
  k_projb<<<1536, 256, 0, stream>>>(xb, bb, p); // 256 m x 6 n
  k_sq   <<<8192, 256, 0, stream>>>(p, sq);
  k_gram <<<1024, 256, 0, stream>>>(p, sq, out); // 64 batches x 16 tiles
}